// Round 10
// baseline (364.695 us; speedup 1.0000x reference)
//
#include <hip/hip_runtime.h>
#include <math.h>

// Problem constants (from reference)
#define B_ 16
#define T_ 4096
#define C_ 512
#define E_ 64
#define K_ 2048
#define N_ (B_*T_)          // 65536
#define ZQ_ELEMS 4194304    // B*E*T

typedef __attribute__((ext_vector_type(8))) short short8;
typedef __attribute__((ext_vector_type(4))) short short4v;
typedef __attribute__((ext_vector_type(4))) float f32x4;

// ws layout (bytes):
//   ehi_sw : [16][8192] bf16 B-frag-tiled codebook hi @ 0       (256 KB)
//   elo_sw : lo plane                              @ 262144     (256 KB)
//   nhcc   : [K] f32 (-0.5*||e_k||^2)              @ 524288     (8 KB)
//   w_hi   : [64][512] bf16                        @ 532480     (64 KB)
//   w_lo   : [64][512] bf16                        @ 598016     (64 KB)
//   hist   : [K] i32                               @ 663552     (8 KB)  <- zeroed by prep
//   loss   : f32                                   @ 671744     (4 B)
//   cnt    : u32 completion counter                @ 671748     (4 B)
#define WS_EHI   0
#define WS_ELO   262144
#define WS_NHCC  524288
#define WS_WHI   532480
#define WS_WLO   598016
#define WS_HIST  663552
#define WS_LOSS  671744
#define WS_CNT   671748

struct HiLo { short hi, lo; };

__device__ __forceinline__ unsigned short rne16(float v) {
    unsigned u = __float_as_uint(v);
    return (unsigned short)((u + 0x7FFFu + ((u >> 16) & 1u)) >> 16);
}
__device__ __forceinline__ HiLo split_rne(float v) {
    HiLo r;
    unsigned hb = rne16(v);
    r.hi = (short)hb;
    float hf = __uint_as_float((unsigned)hb << 16);
    r.lo = (short)rne16(v - hf);
    return r;
}

// ---------------------------------------------------------------------------
// Prep. Blocks 0..63: embed -> B-frag-tiled bf16 hi/lo + nhcc.
//       Blocks 64..95: W -> flat bf16 hi/lo.
//       Block 0 additionally zeroes hist+loss+cnt (replaces the memset
//       dispatch; stream order guarantees completion before fused).
// Tiled layout per 128-k chunk (8192 shorts/plane): slot for (r=k&127, e):
//   kt=r>>4, col=r&15, ks=e>>5, qe=(e>>3)&3 -> ((kt*2+ks)*64 + qe*16 + col)*8 + (e&7)
// so a scan wave's B-frag read (pb + lane*8) is a coalesced 1 KB run directly
// from global (L2-resident).
// ---------------------------------------------------------------------------
__global__ void prep_kernel(const float* __restrict__ embed,
                            const float* __restrict__ W,
                            short* __restrict__ ehi, short* __restrict__ elo,
                            float* __restrict__ nhcc,
                            short* __restrict__ whi, short* __restrict__ wlo,
                            int* __restrict__ hist) {
    const int tid = threadIdx.x;
    if (blockIdx.x == 0) {
        for (int i = tid; i < K_ + 2; i += 256) hist[i] = 0;   // hist + loss + cnt
    }
    if (blockIdx.x < 64) {
        const int row = blockIdx.x * 32 + (tid >> 3);
        const int g = tid & 7;
        const float* src = embed + (size_t)row * 64 + g * 8;
        short8 hv, lv;
        float s = 0.f;
#pragma unroll
        for (int j = 0; j < 8; ++j) {
            float v = src[j];
            s = fmaf(v, v, s);
            HiLo r = split_rne(v);
            hv[j] = r.hi; lv[j] = r.lo;
        }
        const int c128 = row >> 7, r = row & 127;
        const int kt = r >> 4, col = r & 15, ks = g >> 2, qe = g & 3;
        const int slot = (kt * 2 + ks) * 64 + qe * 16 + col;
        *(short8*)(ehi + c128 * 8192 + slot * 8) = hv;
        *(short8*)(elo + c128 * 8192 + slot * 8) = lv;
        s += __shfl_xor(s, 1, 64);
        s += __shfl_xor(s, 2, 64);
        s += __shfl_xor(s, 4, 64);
        if (g == 0) nhcc[row] = -0.5f * s;
    } else {
        int idx = ((blockIdx.x - 64) * 256 + tid) * 4;
        float4 v = *(const float4*)(W + idx);
        short4v h, l;
        HiLo a = split_rne(v.x); h[0] = a.hi; l[0] = a.lo;
        HiLo b = split_rne(v.y); h[1] = b.hi; l[1] = b.lo;
        HiLo c = split_rne(v.z); h[2] = c.hi; l[2] = c.lo;
        HiLo d = split_rne(v.w); h[3] = d.hi; l[3] = d.lo;
        *(short4v*)(whi + idx) = h;
        *(short4v*)(wlo + idx) = l;
    }
}

// ---------------------------------------------------------------------------
// Fused proj+VQ(+finalize) kernel. Block = 64 t-rows, 4 waves, grid 1024.
// Phase 1: 4-way c-split projection (barrier-free loop, wave-private LDS
//   transpose), tree-merge partials, wave 0 parks the h A-frag image in LDS.
//   RACE FIX (r9): wave-0 epilogue folds ALL of M1 into acc BEFORE writing
//   H (H overlaps M1; interleaved read/write corrupted later reads).
// Phase 2: kh=wave codebook scan (32 steps x 24 MFMA, dbuf direct-from-L2),
//   4-way argmax merge, fused gather+transpose.
// Tail: last-block-done pattern folds the finalize dispatch in: threadfence +
//   counter atomicAdd; last block re-reads hist/lossacc via atomic-RMW reads
//   (device coherence point -> safe under XCD non-coherence).
// ---------------------------------------------------------------------------
#define VQ_STEP(H0, H1, L0, L1, SS)                                            \
    {                                                                          \
        const int kk = ((SS) >> 1) * 128 + (kh * 2 + ((SS) & 1)) * 16 + row16; \
        const float ci = nhcc[kk];                                             \
        _Pragma("unroll")                                                      \
        for (int rt = 0; rt < 4; ++rt) {                                       \
            f32x4 a2 = (f32x4){0.f, 0.f, 0.f, 0.f};                            \
            a2 = __builtin_amdgcn_mfma_f32_16x16x32_bf16(a_hi[rt][0], H0, a2, 0, 0, 0); \
            a2 = __builtin_amdgcn_mfma_f32_16x16x32_bf16(a_hi[rt][1], H1, a2, 0, 0, 0); \
            a2 = __builtin_amdgcn_mfma_f32_16x16x32_bf16(a_lo[rt][0], H0, a2, 0, 0, 0); \
            a2 = __builtin_amdgcn_mfma_f32_16x16x32_bf16(a_lo[rt][1], H1, a2, 0, 0, 0); \
            a2 = __builtin_amdgcn_mfma_f32_16x16x32_bf16(a_hi[rt][0], L0, a2, 0, 0, 0); \
            a2 = __builtin_amdgcn_mfma_f32_16x16x32_bf16(a_hi[rt][1], L1, a2, 0, 0, 0); \
            _Pragma("unroll")                                                  \
            for (int rg = 0; rg < 4; ++rg) {                                   \
                float v = a2[rg] + ci;                                         \
                if (v > vmax[rt][rg]) { vmax[rt][rg] = v; vidx[rt][rg] = kk; } \
            }                                                                  \
        }                                                                      \
    }

#define VQ_LOAD(H0, H1, L0, L1, SS)                                            \
    {                                                                          \
        const int c2 = (SS) >> 1, kt2 = kh * 2 + ((SS) & 1);                   \
        const short* pb = ehi + c2 * 8192 + kt2 * 1024;                        \
        const short* pl = elo + c2 * 8192 + kt2 * 1024;                        \
        H0 = *(const short8*)(pb + lane * 8);                                  \
        H1 = *(const short8*)(pb + 512 + lane * 8);                            \
        L0 = *(const short8*)(pl + lane * 8);                                  \
        L1 = *(const short8*)(pl + 512 + lane * 8);                            \
    }

__global__ __launch_bounds__(256, 2) void fused_kernel(
        const float* __restrict__ x,
        const short* __restrict__ whi, const short* __restrict__ wlo,
        const float* __restrict__ bias,
        const short* __restrict__ ehi, const short* __restrict__ elo,
        const float* __restrict__ nhcc,
        const float* __restrict__ embed, float* __restrict__ out,
        int* __restrict__ hist, float* __restrict__ lossacc,
        unsigned* __restrict__ cnt) {
    // LDS plan (36608 B + flag, region reuse sequential + barrier-guarded):
    //   xw   [4][32][66] f32 @ 0      (33792)  phase-1 transpose (wave-private)
    //   M1   [64][68] f32    @ 0      (17408)  merge buf (reuses xw)
    //   M2   [64][68] f32    @ 17408  (17408)
    //   H    [2][8192] short @ 0      (32768)  h image hi|lo (reuses M1/M2;
    //                                          wave 0 folds M1 fully before writing)
    //   tile [64][69] f32    @ 0      (17664)  gather (reuses H)
    //   qsm/vtmp/itmp        @ 34816  (1792)
    __shared__ __align__(16) char smem[36608];
    __shared__ int lastFlag;
    float* xw   = (float*)smem;
    float* M1   = (float*)smem;
    float* M2   = (float*)(smem + 17408);
    short* H    = (short*)smem;
    float* tile = (float*)smem;
    int*   qsm  = (int*)(smem + 34816);
    float* vtmp = (float*)(smem + 35072);
    int*   itmp = (int*)(smem + 35840);

    const int tid = threadIdx.x;
    const int wave = tid >> 6, lane = tid & 63;
    const int row16 = lane & 15, quad = lane >> 4;
    const int blk = blockIdx.x;              // 1024 blocks, 64 t each
    const int b  = blk >> 6;
    const int t0 = (blk & 63) * 64;
    const float* xr = x + (size_t)b * C_ * T_ + t0;
    float* wl = xw + wave * (32 * 66);

    const int c_row = lane >> 4;             // 0..3
    const int c_t4  = (lane & 15) * 4;       // 16 lanes x float4 = 256-B segment
    const int cbase = wave * 128;            // 4-way c-split

    // ---------------- Phase 1: projection (barrier-free loop) ----------------
    f32x4 acc[4][4];
#pragma unroll
    for (int rt = 0; rt < 4; ++rt)
#pragma unroll
        for (int et = 0; et < 4; ++et) acc[rt][et] = (f32x4){0.f, 0.f, 0.f, 0.f};

    float4 xn[8];
#pragma unroll
    for (int q = 0; q < 8; ++q)
        xn[q] = *(const float4*)(xr + (size_t)(cbase + q * 4 + c_row) * T_ + c_t4);

    for (int it = 0; it < 4; ++it) {
        const int c0 = cbase + it * 32;
#pragma unroll
        for (int q = 0; q < 8; ++q) {
            float* d = wl + (q * 4 + c_row) * 66 + c_t4;
            *(float2*)(d)     = make_float2(xn[q].x, xn[q].y);
            *(float2*)(d + 2) = make_float2(xn[q].z, xn[q].w);
        }
        if (it < 3) {
#pragma unroll
            for (int q = 0; q < 8; ++q)
                xn[q] = *(const float4*)(xr + (size_t)(c0 + 32 + q * 4 + c_row) * T_ + c_t4);
        }
#pragma unroll
        for (int rp = 0; rp < 2; ++rp) {
            short8 bh[2], bl[2];
#pragma unroll
            for (int rr = 0; rr < 2; ++rr) {
                const int rt = rp * 2 + rr;
#pragma unroll
                for (int j = 0; j < 8; ++j) {
                    float v = wl[(quad * 8 + j) * 66 + rt * 16 + row16];
                    HiLo r = split_rne(v);
                    bh[rr][j] = r.hi; bl[rr][j] = r.lo;
                }
            }
#pragma unroll
            for (int et = 0; et < 4; ++et) {
                size_t aoff = (size_t)(et * 16 + row16) * C_ + c0 + quad * 8;
                short8 ah = *(const short8*)(whi + aoff);
                short8 al = *(const short8*)(wlo + aoff);
#pragma unroll
                for (int rr = 0; rr < 2; ++rr) {
                    const int rt = rp * 2 + rr;
                    acc[rt][et] = __builtin_amdgcn_mfma_f32_16x16x32_bf16(ah, bh[rr], acc[rt][et], 0, 0, 0);
                    acc[rt][et] = __builtin_amdgcn_mfma_f32_16x16x32_bf16(al, bh[rr], acc[rt][et], 0, 0, 0);
                    acc[rt][et] = __builtin_amdgcn_mfma_f32_16x16x32_bf16(ah, bl[rr], acc[rt][et], 0, 0, 0);
                    acc[rt][et] = __builtin_amdgcn_mfma_f32_16x16x32_bf16(al, bl[rr], acc[rt][et], 0, 0, 0);
                }
            }
        }
    }

    // ---- tree-merge the 4 c-partials in f32 via LDS ----
    // D layout: t = rt*16 + row16, e = et*16 + quad*4 + r.
    __syncthreads();                         // xw dead
    if (wave == 1 || wave == 3) {
        float* Mx = (wave == 1) ? M1 : M2;
#pragma unroll
        for (int rt = 0; rt < 4; ++rt)
#pragma unroll
            for (int et = 0; et < 4; ++et)
#pragma unroll
                for (int r = 0; r < 4; ++r)
                    Mx[(et * 16 + quad * 4 + r) * 68 + rt * 16 + row16] = acc[rt][et][r];
    }
    __syncthreads();
    if (wave == 0 || wave == 2) {
        float* Mx = (wave == 0) ? M1 : M2;
#pragma unroll
        for (int rt = 0; rt < 4; ++rt)
#pragma unroll
            for (int et = 0; et < 4; ++et)
#pragma unroll
                for (int r = 0; r < 4; ++r)
                    acc[rt][et][r] += Mx[(et * 16 + quad * 4 + r) * 68 + rt * 16 + row16];
    }
    __syncthreads();
    if (wave == 2) {
#pragma unroll
        for (int rt = 0; rt < 4; ++rt)
#pragma unroll
            for (int et = 0; et < 4; ++et)
#pragma unroll
                for (int r = 0; r < 4; ++r)
                    M1[(et * 16 + quad * 4 + r) * 68 + rt * 16 + row16] = acc[rt][et][r];
    }
    __syncthreads();
    if (wave == 0) {
        // RACE FIX: fold ALL of M1 into acc before any H write (H overlaps
        // M1; same-wave LDS ops process in order, so read-all-then-write
        // is safe with no barrier).
#pragma unroll
        for (int rt = 0; rt < 4; ++rt)
#pragma unroll
            for (int et = 0; et < 4; ++et)
#pragma unroll
                for (int r = 0; r < 4; ++r)
                    acc[rt][et][r] += M1[(et * 16 + quad * 4 + r) * 68 + rt * 16 + row16];

        float hh = 0.f;
#pragma unroll
        for (int rt = 0; rt < 4; ++rt) {
#pragma unroll
            for (int et = 0; et < 4; ++et) {
                float4 bv = *(const float4*)(bias + et * 16 + quad * 4);
                f32x4 a = acc[rt][et];
                a[0] += bv.x; a[1] += bv.y; a[2] += bv.z; a[3] += bv.w;
                hh = fmaf(a[0], a[0], hh); hh = fmaf(a[1], a[1], hh);
                hh = fmaf(a[2], a[2], hh); hh = fmaf(a[3], a[3], hh);
                short4v hv, lv;
#pragma unroll
                for (int r = 0; r < 4; ++r) {
                    HiLo sp = split_rne(a[r]);
                    hv[r] = sp.hi; lv[r] = sp.lo;
                }
                // A-frag tiled slot (w2 = rt), matches the phase-2 reader.
                const int ks = et >> 1;
                const int qe = (et & 1) * 2 + (quad >> 1);
                const int j0 = (quad & 1) * 4;
                const int sl = ((rt * 2 + ks) * 64 + qe * 16 + row16) * 8 + j0;
                *(short4v*)(H + sl) = hv;
                *(short4v*)(H + 8192 + sl) = lv;
            }
        }
#pragma unroll
        for (int m = 1; m < 64; m <<= 1) hh += __shfl_xor(hh, m, 64);
        if (lane == 0) atomicAdd(lossacc, hh);
    }
    __syncthreads();                         // H ready

    // ---------------- Phase 2: VQ scan (kh = wave) ----------------
    const int kh = wave;
    short8 a_hi[4][2], a_lo[4][2];
#pragma unroll
    for (int rt = 0; rt < 4; ++rt)
#pragma unroll
        for (int ks = 0; ks < 2; ++ks) {
            const int sl = ((rt * 2 + ks) * 64 + lane) * 8;
            a_hi[rt][ks] = *(const short8*)(H + sl);
            a_lo[rt][ks] = *(const short8*)(H + 8192 + sl);
        }

    float vmax[4][4];
    int   vidx[4][4];
#pragma unroll
    for (int rt = 0; rt < 4; ++rt)
#pragma unroll
        for (int rg = 0; rg < 4; ++rg) { vmax[rt][rg] = -3.4e38f; vidx[rt][rg] = 0; }

    short8 pAh0, pAh1, pAl0, pAl1;
    short8 pBh0, pBh1, pBl0, pBl1;
    VQ_LOAD(pAh0, pAh1, pAl0, pAl1, 0);
    for (int s = 0; s < 32; s += 2) {
        VQ_LOAD(pBh0, pBh1, pBl0, pBl1, s + 1);
        VQ_STEP(pAh0, pAh1, pAl0, pAl1, s);
        if (s + 2 < 32) VQ_LOAD(pAh0, pAh1, pAl0, pAl1, s + 2);
        VQ_STEP(pBh0, pBh1, pBl0, pBl1, s + 1);
    }

    // 16-lane k-reduce (tie -> lowest idx), then 4-way kh merge via LDS.
    float s_loss = 0.f;
#pragma unroll
    for (int rt = 0; rt < 4; ++rt)
#pragma unroll
        for (int rg = 0; rg < 4; ++rg) {
            float v = vmax[rt][rg];
            int ix = vidx[rt][rg];
#pragma unroll
            for (int m = 1; m < 16; m <<= 1) {
                float ov = __shfl_xor(v, m, 64);
                int   oi = __shfl_xor(ix, m, 64);
                if (ov > v || (ov == v && oi < ix)) { v = ov; ix = oi; }
            }
            vmax[rt][rg] = v; vidx[rt][rg] = ix;
        }
    if (kh >= 1 && row16 == 0) {
#pragma unroll
        for (int rt = 0; rt < 4; ++rt)
#pragma unroll
            for (int rg = 0; rg < 4; ++rg) {
                const int row = rt * 16 + quad * 4 + rg;   // local 0..63
                vtmp[(kh - 1) * 64 + row] = vmax[rt][rg];
                itmp[(kh - 1) * 64 + row] = vidx[rt][rg];
            }
    }
    __syncthreads();
    if (kh == 0) {
        if (row16 == 0) {
#pragma unroll
            for (int rt = 0; rt < 4; ++rt)
#pragma unroll
                for (int rg = 0; rg < 4; ++rg) {
                    const int row = rt * 16 + quad * 4 + rg;
                    float v = vmax[rt][rg];
                    int ix = vidx[rt][rg];
#pragma unroll
                    for (int p = 0; p < 3; ++p) {
                        const float ov = vtmp[p * 64 + row];
                        const int   oi = itmp[p * 64 + row];
                        if (ov > v || (ov == v && oi < ix)) { v = ov; ix = oi; }
                    }
                    qsm[row] = ix;
                    atomicAdd(&hist[ix], 1);
                    s_loss += v;
                }
        }
        s_loss += __shfl_xor(s_loss, 16, 64);
        s_loss += __shfl_xor(s_loss, 32, 64);
        if (lane == 0) atomicAdd(lossacc, -2.f * s_loss);
    }
    __syncthreads();                         // qsm ready; H dead -> tile reuse OK

    // ---------------- Fused gather + transpose (64 rows) ----------------
    {
        const int r = tid >> 2, piece = tid & 3;
        const float* src = embed + (size_t)qsm[r] * 64 + piece * 16;
        float* dst = tile + r * 69 + piece * 16;
#pragma unroll
        for (int j = 0; j < 4; ++j)
            *(float4*)(dst + j * 4) = *(const float4*)(src + j * 4);
    }
    __syncthreads();
    {
        const int tt = tid & 63;
        const int eo = tid >> 6;               // 0..3
        float* ob = out + ((size_t)b * 64) * T_ + t0;
#pragma unroll
        for (int j = 0; j < 16; ++j) {
            const int e = j * 4 + eo;
            ob[(size_t)e * T_ + tt] = tile[tt * 69 + e];
        }
    }

    // ---------------- Last-block finalize (folds the 3rd dispatch) ----------
    __threadfence();                          // order this block's atomics
    __syncthreads();
    if (tid == 0) {
        unsigned done = atomicAdd(cnt, 1u);
        lastFlag = (done == 1023u);
    }
    __syncthreads();
    if (lastFlag) {
        float s = 0.f;
        for (int k = tid; k < K_; k += 256) {
            int h = atomicAdd(&hist[k], 0);   // coherence-point read
            float p = (float)h * (1.f / 65536.f);
            s -= p * logf(p + 1e-10f);
        }
#pragma unroll
        for (int m = 1; m < 64; m <<= 1) s += __shfl_xor(s, m, 64);
        if ((tid & 63) == 0) vtmp[tid >> 6] = s;
        __syncthreads();
        if (tid == 0) {
            float lp = vtmp[0] + vtmp[1] + vtmp[2] + vtmp[3];
            float la = atomicAdd(lossacc, 0.f);
            out[ZQ_ELEMS] = 0.25f * la / (float)ZQ_ELEMS;    // loss
            out[ZQ_ELEMS + 17] = lp;                          // log_perplexity
        }
        if (tid < 16) out[ZQ_ELEMS + 1 + tid] = logf(2048.f) * 4096.f;  // kldiv_r
    }
}

// ---------------------------------------------------------------------------
extern "C" void kernel_launch(void* const* d_in, const int* in_sizes, int n_in,
                              void* d_out, int out_size, void* d_ws, size_t ws_size,
                              hipStream_t stream) {
    const float* x      = (const float*)d_in[0];
    const float* proj_w = (const float*)d_in[1];
    const float* proj_b = (const float*)d_in[2];
    const float* embed  = (const float*)d_in[3];
    float* out = (float*)d_out;
    char* ws = (char*)d_ws;

    short* e_hi = (short*)(ws + WS_EHI);
    short* e_lo = (short*)(ws + WS_ELO);
    float* nhcc = (float*)(ws + WS_NHCC);
    short* w_hi = (short*)(ws + WS_WHI);
    short* w_lo = (short*)(ws + WS_WLO);
    int*   hist = (int*)(ws + WS_HIST);
    float* lossac = (float*)(ws + WS_LOSS);
    unsigned* cnt = (unsigned*)(ws + WS_CNT);

    prep_kernel<<<96, 256, 0, stream>>>(embed, proj_w, e_hi, e_lo, nhcc,
                                        w_hi, w_lo, hist);
    fused_kernel<<<1024, 256, 0, stream>>>(x, w_hi, w_lo, proj_b,
                                           e_hi, e_lo, nhcc, embed, out,
                                           hist, lossac, cnt);
}